// Round 5
// baseline (675.694 us; speedup 1.0000x reference)
//
#include <hip/hip_runtime.h>
#include <hip/hip_bf16.h>

#define N_NODES 100000
#define N_EDGES 600000
#define N_LABELS 200000
#define DIM 128
#define NPARTS 391           // ceil(N_NODES/256)
#define NT_TILES 6250        // N_NODES / 16 exactly
#define GEMM_GRID 512
#define AGG_BLOCKS 1563      // ceil(N_NODES/64)
#define ACC_STRIDE 130       // 128 + 2 pad: bank offset 2 per node row (16 banks @4-way max)

using short4v = __attribute__((ext_vector_type(4))) short;
using short8 = __attribute__((ext_vector_type(8))) short;
using f32x2  = __attribute__((ext_vector_type(2))) float;
using f32x4  = __attribute__((ext_vector_type(4))) float;

__device__ __forceinline__ float b2f(short s) {
    union { unsigned u; float f; } c;
    c.u = ((unsigned)(unsigned short)s) << 16;
    return c.f;
}
__device__ __forceinline__ short f2b(float f) {
    __hip_bfloat16 h = __float2bfloat16(f);
    return *reinterpret_cast<short*>(&h);
}

// ---------------- prep: BT1 (bf16, 256x128 K-major) + u/v projection vectors + c consts ----------
// u_p = W2l @ Wlin[:128], u_q = W2l @ Wlin[128:], v_p = W2r @ wp, v_q = W2r @ wq,
// c = (b2.wp, b2.wq).  p[n] = mean_nbrs(x1.u_p) + x1[n].v_p + c.x
__global__ void prep_k(const float* __restrict__ W1l, const float* __restrict__ W1r,
                       short* __restrict__ BT1,
                       const float* __restrict__ W2l, const float* __restrict__ W2r,
                       const float* __restrict__ Wlin, const float* __restrict__ b2,
                       float* __restrict__ up, float* __restrict__ uq,
                       float* __restrict__ vp, float* __restrict__ vq,
                       float2* __restrict__ cpq) {
    int b = blockIdx.x;
    int t = threadIdx.x;
    if (b < 128) {
        int i = b * 256 + t;                 // 32768 = 256 x 128
        int n = i >> 7, k = i & 127;
        float v = (n < 128) ? W1l[k * 128 + n] : W1r[k * 128 + (n - 128)];
        BT1[n * 128 + k] = f2b(v);
    } else if (b == 128) {
        const float* W = (t < 128) ? W2l : W2r;
        int k = t & 127;
        float s0 = 0.f, s1 = 0.f;
        for (int n = 0; n < 128; ++n) {
            float w = W[k * 128 + n];
            s0 += w * Wlin[n];
            s1 += w * Wlin[128 + n];
        }
        if (t < 128) { up[k] = s0; uq[k] = s1; }
        else         { vp[k] = s0; vq[k] = s1; }
    } else {
        if (t < 64) {
            float p0 = b2[t] * Wlin[t] + b2[t + 64] * Wlin[t + 64];
            float q0 = b2[t] * Wlin[128 + t] + b2[t + 64] * Wlin[192 + t];
#pragma unroll
            for (int m = 1; m <= 32; m <<= 1) {
                p0 += __shfl_xor(p0, m, 64);
                q0 += __shfl_xor(q0, m, 64);
            }
            if (t == 0) *cpq = make_float2(p0, q0);
        }
    }
}

// ---------------- CSR build ----------------

__global__ void count_k(const int* __restrict__ ei, int* __restrict__ cnt) {
    int e = blockIdx.x * blockDim.x + threadIdx.x;
    if (e < N_EDGES) atomicAdd(&cnt[ei[N_EDGES + e]], 1);
}

__global__ void scan1_k(const int* __restrict__ cnt, int* __restrict__ rowptr,
                        int* __restrict__ partials) {
    __shared__ int s[256];
    int t = threadIdx.x;
    int i = blockIdx.x * 256 + t;
    int v = (i < N_NODES) ? cnt[i] : 0;
    s[t] = v;
    __syncthreads();
    for (int off = 1; off < 256; off <<= 1) {
        int x = s[t];
        int y = (t >= off) ? s[t - off] : 0;
        __syncthreads();
        s[t] = x + y;
        __syncthreads();
    }
    if (i < N_NODES) rowptr[i] = s[t] - v;      // block-local exclusive
    if (t == 255) partials[blockIdx.x] = s[255];
}

// fused scan2+scan3: every block redundantly scans the 391 partials in LDS,
// then applies its base to its 256 rowptr entries.
__global__ void scanB_k(const int* __restrict__ partials, int* __restrict__ rowptr,
                        int* __restrict__ widx) {
    __shared__ int s[512];
    __shared__ int base_s;
    int t = threadIdx.x;                         // 512 threads
    int v = (t < NPARTS) ? partials[t] : 0;
    s[t] = v;
    __syncthreads();
    for (int off = 1; off < 512; off <<= 1) {
        int x = s[t];
        int y = (t >= off) ? s[t - off] : 0;
        __syncthreads();
        s[t] = x + y;
        __syncthreads();
    }
    int b = blockIdx.x;
    if (t == 0) base_s = (b > 0) ? s[b - 1] : 0;
    if (b == 0 && t == 0) rowptr[N_NODES] = s[NPARTS - 1];
    __syncthreads();
    if (t < 256) {
        int i = b * 256 + t;
        if (i < N_NODES) {
            int r = rowptr[i] + base_s;
            rowptr[i] = r;
            widx[i] = r;
        }
    }
}

__global__ void fill_k(const int* __restrict__ ei, int* __restrict__ widx,
                       int* __restrict__ adj) {
    int e = blockIdx.x * blockDim.x + threadIdx.x;
    if (e < N_EDGES) {
        int d = ei[N_EDGES + e];
        int pos = atomicAdd(&widx[d], 1);
        adj[pos] = ei[e];
    }
}

// ---------------- GEMM1: [Hl|Hr] = bf16(emb) @ [W1l|W1r]  (weight-resident MFMA) ----------------

__global__ __launch_bounds__(256, 2) void gemm_k(const float* __restrict__ Af,
                                                 const short* __restrict__ BT,
                                                 short* __restrict__ Hl,
                                                 short* __restrict__ Hr) {
    int lane = threadIdx.x & 63;
    int wave = threadIdx.x >> 6;
    int quad = lane >> 4;
    int l16  = lane & 15;
    int half = wave & 1;
    int pair = blockIdx.x * 2 + (wave >> 1);
    const int P = GEMM_GRID * 2;

    short* __restrict__ H = half ? Hr : Hl;

    short8 Wf[8][4];
#pragma unroll
    for (int t = 0; t < 8; ++t)
#pragma unroll
        for (int kk = 0; kk < 4; ++kk)
            Wf[t][kk] = *(const short8*)(BT + (half * 128 + t * 16 + l16) * DIM + kk * 32 + quad * 8);

    for (int s = pair; s < NT_TILES; s += P) {
        long arow = (long)s * 16 + l16;

        short8 xf[4];
#pragma unroll
        for (int kk = 0; kk < 4; ++kk) {
            f32x4 a0 = *(const f32x4*)(Af + arow * DIM + kk * 32 + quad * 8);
            f32x4 a1 = *(const f32x4*)(Af + arow * DIM + kk * 32 + quad * 8 + 4);
#pragma unroll
            for (int j = 0; j < 4; ++j) { xf[kk][j] = f2b(a0[j]); xf[kk][4 + j] = f2b(a1[j]); }
        }

        f32x4 acc[8];
#pragma unroll
        for (int t = 0; t < 8; ++t)
#pragma unroll
            for (int r = 0; r < 4; ++r) acc[t][r] = 0.f;

#pragma unroll
        for (int kk = 0; kk < 4; ++kk)
#pragma unroll
            for (int t = 0; t < 8; ++t)
                acc[t] = __builtin_amdgcn_mfma_f32_16x16x32_bf16(Wf[t][kk], xf[kk], acc[t], 0, 0, 0);

#pragma unroll
        for (int t = 0; t < 8; ++t) {
            short4v o;
#pragma unroll
            for (int r = 0; r < 4; ++r) o[r] = f2b(acc[t][r]);
            *(short4v*)(H + arow * DIM + t * 16 + quad * 4) = o;
        }
    }
}

// ---------------- layer-1 agg: block-cooperative, edge-parallel ----------------
// Block owns 64 consecutive dst nodes (contiguous CSR edge range). Edge-parallel
// accumulation into LDS (fp32, padded stride), then node-parallel epilogue computing
// x1 = relu(mean + Hr + b1) and the 4 projection dots S=(x.up,x.uq), T=(x.vp,x.vq).
__global__ __launch_bounds__(256) void agg1_k(const short* __restrict__ Hl,
                                              const short* __restrict__ Hr,
                                              const int* __restrict__ rowptr,
                                              const int* __restrict__ adj,
                                              const float* __restrict__ b1,
                                              const float* __restrict__ up, const float* __restrict__ uq,
                                              const float* __restrict__ vp, const float* __restrict__ vq,
                                              float2* __restrict__ S, float2* __restrict__ T) {
    __shared__ float acc[64 * ACC_STRIDE];
    __shared__ int srow[65];

    int tid = threadIdx.x;
    int n0 = blockIdx.x * 64;

    if (tid < 65) {
        int n = n0 + tid;
        srow[tid] = rowptr[n <= N_NODES ? n : N_NODES];
    }
    for (int i = tid; i < 64 * ACC_STRIDE; i += 256) acc[i] = 0.f;
    __syncthreads();

    int group = tid >> 4;        // 0..15 block-wide edge groups
    int l16   = tid & 15;
    int f0    = l16 << 3;        // 8 features per lane
    int ebeg = srow[0], eend = srow[64];

    // edge-parallel: each group handles one edge; iterations independent.
#pragma unroll 2
    for (int e = ebeg + group; e < eend; e += 16) {
        int src = adj[e];                                   // group-broadcast load
        int lo = 0, hi = 64;
#pragma unroll
        for (int it = 0; it < 6; ++it) {                    // binsearch local dst
            int mid = (lo + hi) >> 1;
            bool c = srow[mid] <= e;
            lo = c ? mid : lo;
            hi = c ? hi : mid;
        }
        short8 h = *(const short8*)(Hl + (long)src * DIM + f0);
        float* ar = &acc[lo * ACC_STRIDE + f0];
#pragma unroll
        for (int j = 0; j < 8; ++j) unsafeAtomicAdd(&ar[j], b2f(h[j]));
    }
    __syncthreads();

    // epilogue: group g handles local nodes g, g+16, g+32, g+48
#pragma unroll
    for (int c = 0; c < 4; ++c) {
        int ln = group + (c << 4);
        int node = n0 + ln;
        if (node >= N_NODES) continue;
        int deg = srow[ln + 1] - srow[ln];
        float inv = deg > 0 ? 1.f / (float)deg : 0.f;

        const float* ar = &acc[ln * ACC_STRIDE + f0];
        f32x2 s0 = *(const f32x2*)(ar);
        f32x2 s1 = *(const f32x2*)(ar + 2);
        f32x2 s2 = *(const f32x2*)(ar + 4);
        f32x2 s3 = *(const f32x2*)(ar + 6);
        float sm[8] = { s0[0], s0[1], s1[0], s1[1], s2[0], s2[1], s3[0], s3[1] };

        f32x4 bb0 = *(const f32x4*)(b1 + f0);
        f32x4 bb1 = *(const f32x4*)(b1 + f0 + 4);
        short8 hr = *(const short8*)(Hr + (long)node * DIM + f0);
        float x[8];
#pragma unroll
        for (int j = 0; j < 8; ++j) {
            float bias = (j < 4) ? bb0[j] : bb1[j - 4];
            x[j] = fmaxf(sm[j] * inv + b2f(hr[j]) + bias, 0.f);
        }

        f32x4 up0 = *(const f32x4*)(up + f0), up1 = *(const f32x4*)(up + f0 + 4);
        f32x4 uq0 = *(const f32x4*)(uq + f0), uq1 = *(const f32x4*)(uq + f0 + 4);
        f32x4 vp0 = *(const f32x4*)(vp + f0), vp1 = *(const f32x4*)(vp + f0 + 4);
        f32x4 vq0 = *(const f32x4*)(vq + f0), vq1 = *(const f32x4*)(vq + f0 + 4);
        float ap = 0.f, aq = 0.f, tp = 0.f, tq = 0.f;
#pragma unroll
        for (int j = 0; j < 8; ++j) {
            float upj = (j < 4) ? up0[j] : up1[j - 4];
            float uqj = (j < 4) ? uq0[j] : uq1[j - 4];
            float vpj = (j < 4) ? vp0[j] : vp1[j - 4];
            float vqj = (j < 4) ? vq0[j] : vq1[j - 4];
            ap += x[j] * upj;
            aq += x[j] * uqj;
            tp += x[j] * vpj;
            tq += x[j] * vqj;
        }
#pragma unroll
        for (int m = 1; m <= 8; m <<= 1) {         // reduce across the 16-lane group
            ap += __shfl_xor(ap, m, 64);
            aq += __shfl_xor(aq, m, 64);
            tp += __shfl_xor(tp, m, 64);
            tq += __shfl_xor(tq, m, 64);
        }
        if (l16 == 0) {
            S[node] = make_float2(ap, aq);
            T[node] = make_float2(tp, tq);
        }
    }
}

// layer-2: p[n] = mean_nbrs(S.x) + T.x + c.x ; q likewise. 8B gather per edge.
__global__ void agg2_k(const int* __restrict__ rowptr, const int* __restrict__ adj,
                       const float2* __restrict__ S, const float2* __restrict__ T,
                       const float2* __restrict__ cpq,
                       float* __restrict__ p, float* __restrict__ q) {
    int lane = threadIdx.x & 63;
    int wavei = blockIdx.x * 4 + (threadIdx.x >> 6);
    int slot = lane & 3;
    int node = wavei * 16 + (lane >> 2);
    if (node >= N_NODES) return;
    int beg = rowptr[node], end = rowptr[node + 1];
    float sp = 0.f, sq = 0.f;
    for (int e = beg + slot; e < end; e += 4) {
        float2 v = S[adj[e]];
        sp += v.x; sq += v.y;
    }
    sp += __shfl_xor(sp, 1, 64); sp += __shfl_xor(sp, 2, 64);
    sq += __shfl_xor(sq, 1, 64); sq += __shfl_xor(sq, 2, 64);
    if (slot == 0) {
        int deg = end - beg;
        float inv = deg > 0 ? 1.f / (float)deg : 0.f;
        float2 t = T[node];
        float2 c = *cpq;
        p[node] = sp * inv + t.x + c.x;
        q[node] = sq * inv + t.y + c.y;
    }
}

__global__ void out_k(const int* __restrict__ eli, const float* __restrict__ p,
                      const float* __restrict__ q, const float* __restrict__ blin,
                      float* __restrict__ out) {
    int i = blockIdx.x * blockDim.x + threadIdx.x;
    if (i < N_LABELS) out[i] = p[eli[i]] + q[eli[N_LABELS + i]] + blin[0];
}

// ---------------- launch ----------------

extern "C" void kernel_launch(void* const* d_in, const int* in_sizes, int n_in,
                              void* d_out, int out_size, void* d_ws, size_t ws_size,
                              hipStream_t stream) {
    const int*   edge_index = (const int*)d_in[0];
    const int*   eli        = (const int*)d_in[1];
    const float* emb        = (const float*)d_in[2];
    const float* W1l        = (const float*)d_in[3];
    const float* b1         = (const float*)d_in[4];
    const float* W1r        = (const float*)d_in[5];
    const float* W2l        = (const float*)d_in[6];
    const float* b2         = (const float*)d_in[7];
    const float* W2r        = (const float*)d_in[8];
    const float* Wlin       = (const float*)d_in[9];
    const float* blin       = (const float*)d_in[10];
    float* out = (float*)d_out;

    char* ws = (char*)d_ws;
    size_t off = 0;
    auto alloc = [&](size_t bytes) -> void* {
        off = (off + 255) & ~(size_t)255;
        void* ptr = ws + off;
        off += bytes;
        return ptr;
    };

    short* Hl  = (short*)alloc((size_t)N_NODES * DIM * 2);
    short* Hr  = (short*)alloc((size_t)N_NODES * DIM * 2);
    short* BT1 = (short*)alloc(256 * 128 * 2);
    float* up = (float*)alloc(128 * 4);
    float* uq = (float*)alloc(128 * 4);
    float* vp = (float*)alloc(128 * 4);
    float* vq = (float*)alloc(128 * 4);
    float2* cpq = (float2*)alloc(8);
    int* cnt      = (int*)alloc((size_t)N_NODES * 4);
    int* rowptr   = (int*)alloc((size_t)(N_NODES + 1) * 4);
    int* widx     = (int*)alloc((size_t)N_NODES * 4);
    int* adj      = (int*)alloc((size_t)N_EDGES * 4);
    int* partials = (int*)alloc(NPARTS * 4);
    float2* S     = (float2*)alloc((size_t)N_NODES * 8);
    float2* T     = (float2*)alloc((size_t)N_NODES * 8);
    float* p      = (float*)alloc((size_t)N_NODES * 4);
    float* q      = (float*)alloc((size_t)N_NODES * 4);

    hipMemsetAsync(cnt, 0, (size_t)N_NODES * 4, stream);

    prep_k<<<130, 256, 0, stream>>>(W1l, W1r, BT1, W2l, W2r, Wlin, b2, up, uq, vp, vq, cpq);

    // CSR build
    count_k<<<(N_EDGES + 255) / 256, 256, 0, stream>>>(edge_index, cnt);
    scan1_k<<<NPARTS, 256, 0, stream>>>(cnt, rowptr, partials);
    scanB_k<<<NPARTS, 512, 0, stream>>>(partials, rowptr, widx);
    fill_k<<<(N_EDGES + 255) / 256, 256, 0, stream>>>(edge_index, widx, adj);

    // layer 1 GEMM (emb f32 read + bf16 convert fused)
    gemm_k<<<GEMM_GRID, 256, 0, stream>>>(emb, BT1, Hl, Hr);

    // layer-1 aggregation (block-cooperative) fused with layer-2 projections
    agg1_k<<<AGG_BLOCKS, 256, 0, stream>>>(Hl, Hr, rowptr, adj, b1, up, uq, vp, vq, S, T);

    // layer-2 (8B-per-edge gather) + predictor
    agg2_k<<<(N_NODES + 63) / 64, 256, 0, stream>>>(rowptr, adj, S, T, cpq, p, q);
    out_k<<<(N_LABELS + 255) / 256, 256, 0, stream>>>(eli, p, q, blin, out);
}

// Round 6
// 269.295 us; speedup vs baseline: 2.5091x; 2.5091x over previous
//
#include <hip/hip_runtime.h>
#include <hip/hip_bf16.h>

#define N_NODES 100000
#define N_EDGES 600000
#define N_LABELS 200000
#define DIM 128
#define NPARTS 391           // ceil(N_NODES/256)
#define NT_TILES 6250        // N_NODES / 16 exactly
#define GEMM_GRID 512

using short4v = __attribute__((ext_vector_type(4))) short;
using short8 = __attribute__((ext_vector_type(8))) short;
using f32x2  = __attribute__((ext_vector_type(2))) float;
using f32x4  = __attribute__((ext_vector_type(4))) float;
using u32x2  = __attribute__((ext_vector_type(2))) unsigned;
using u32x4  = __attribute__((ext_vector_type(4))) unsigned;

__device__ __forceinline__ float b2f(short s) {
    union { unsigned u; float f; } c;
    c.u = ((unsigned)(unsigned short)s) << 16;
    return c.f;
}
// unpack 2 bf16 packed in a dword -> 2 exact f32 (2 VALU ops)
__device__ __forceinline__ f32x2 b2f2(unsigned u) {
    union { unsigned u; float f; } lo, hi;
    lo.u = u << 16;
    hi.u = u & 0xffff0000u;
    f32x2 r; r[0] = lo.f; r[1] = hi.f;
    return r;
}
__device__ __forceinline__ short f2b(float f) {
    __hip_bfloat16 h = __float2bfloat16(f);
    return *reinterpret_cast<short*>(&h);
}
// pack 2 f32 -> 2 bf16 (RNE, same numerics as __float2bfloat16)
__device__ __forceinline__ unsigned f2b2u(float x, float y) {
    __hip_bfloat162 h = __float22bfloat162_rn(make_float2(x, y));
    return *reinterpret_cast<unsigned*>(&h);
}

// ---------------- prep: BT1 + u/v projection vectors + c consts + cnt zero-init ----------
// u_p = W2l @ Wlin[:128], u_q = W2l @ Wlin[128:], v_p = W2r @ wp, v_q = W2r @ wq,
// c = (b2.wp, b2.wq).  p[n] = mean_nbrs(x1.u_p) + x1[n].v_p + c.x
__global__ void prep_k(const float* __restrict__ W1l, const float* __restrict__ W1r,
                       short* __restrict__ BT1,
                       const float* __restrict__ W2l, const float* __restrict__ W2r,
                       const float* __restrict__ Wlin, const float* __restrict__ b2,
                       float* __restrict__ up, float* __restrict__ uq,
                       float* __restrict__ vp, float* __restrict__ vq,
                       float2* __restrict__ cpq, int* __restrict__ cnt) {
    int b = blockIdx.x;
    int t = threadIdx.x;
    if (b < 128) {
        int i = b * 256 + t;                 // 32768 = 256 x 128
        int n = i >> 7, k = i & 127;
        float v = (n < 128) ? W1l[k * 128 + n] : W1r[k * 128 + (n - 128)];
        BT1[n * 128 + k] = f2b(v);
    } else if (b == 128) {
        const float* W = (t < 128) ? W2l : W2r;
        int k = t & 127;
        float s0 = 0.f, s1 = 0.f;
        for (int n = 0; n < 128; ++n) {
            float w = W[k * 128 + n];
            s0 += w * Wlin[n];
            s1 += w * Wlin[128 + n];
        }
        if (t < 128) { up[k] = s0; uq[k] = s1; }
        else         { vp[k] = s0; vq[k] = s1; }
    } else if (b == 129) {
        if (t < 64) {
            float p0 = b2[t] * Wlin[t] + b2[t + 64] * Wlin[t + 64];
            float q0 = b2[t] * Wlin[128 + t] + b2[t + 64] * Wlin[192 + t];
#pragma unroll
            for (int m = 1; m <= 32; m <<= 1) {
                p0 += __shfl_xor(p0, m, 64);
                q0 += __shfl_xor(q0, m, 64);
            }
            if (t == 0) *cpq = make_float2(p0, q0);
        }
    } else {
        int i = (b - 130) * 256 + t;
        if (i < N_NODES) cnt[i] = 0;
    }
}

// ---------------- CSR build ----------------

__global__ void count_k(const int* __restrict__ ei, int* __restrict__ cnt) {
    int e = blockIdx.x * blockDim.x + threadIdx.x;
    if (e < N_EDGES) atomicAdd(&cnt[ei[N_EDGES + e]], 1);
}

__global__ void scan1_k(const int* __restrict__ cnt, int* __restrict__ rowptr,
                        int* __restrict__ partials) {
    __shared__ int s[256];
    int t = threadIdx.x;
    int i = blockIdx.x * 256 + t;
    int v = (i < N_NODES) ? cnt[i] : 0;
    s[t] = v;
    __syncthreads();
    for (int off = 1; off < 256; off <<= 1) {
        int x = s[t];
        int y = (t >= off) ? s[t - off] : 0;
        __syncthreads();
        s[t] = x + y;
        __syncthreads();
    }
    if (i < N_NODES) rowptr[i] = s[t] - v;      // block-local exclusive
    if (t == 255) partials[blockIdx.x] = s[255];
}

// fused scan2+scan3: every block redundantly scans the 391 partials in LDS,
// then applies its base to its 256 rowptr entries.
__global__ void scanB_k(const int* __restrict__ partials, int* __restrict__ rowptr,
                        int* __restrict__ widx) {
    __shared__ int s[512];
    __shared__ int base_s;
    int t = threadIdx.x;                         // 512 threads
    int v = (t < NPARTS) ? partials[t] : 0;
    s[t] = v;
    __syncthreads();
    for (int off = 1; off < 512; off <<= 1) {
        int x = s[t];
        int y = (t >= off) ? s[t - off] : 0;
        __syncthreads();
        s[t] = x + y;
        __syncthreads();
    }
    int b = blockIdx.x;
    if (t == 0) base_s = (b > 0) ? s[b - 1] : 0;
    if (b == 0 && t == 0) rowptr[N_NODES] = s[NPARTS - 1];
    __syncthreads();
    if (t < 256) {
        int i = b * 256 + t;
        if (i < N_NODES) {
            int r = rowptr[i] + base_s;
            rowptr[i] = r;
            widx[i] = r;
        }
    }
}

__global__ void fill_k(const int* __restrict__ ei, int* __restrict__ widx,
                       int* __restrict__ adj) {
    int e = blockIdx.x * blockDim.x + threadIdx.x;
    if (e < N_EDGES) {
        int d = ei[N_EDGES + e];
        int pos = atomicAdd(&widx[d], 1);
        adj[pos] = ei[e];
    }
}

// ---------------- GEMM1: [Hl|Hr] = bf16(emb) @ [W1l|W1r]  (weight-resident MFMA) ----------------
// A_op = weight frags (m = out feature), B_op = node rows (n = node).
// D lane layout: feature = quad*4+r (4 consecutive), node = l16 -> 8B packed stores.

__global__ __launch_bounds__(256, 2) void gemm_k(const float* __restrict__ Af,
                                                 const short* __restrict__ BT,
                                                 short* __restrict__ Hl,
                                                 short* __restrict__ Hr) {
    int lane = threadIdx.x & 63;
    int wave = threadIdx.x >> 6;
    int quad = lane >> 4;
    int l16  = lane & 15;
    int half = wave & 1;
    int pair = blockIdx.x * 2 + (wave >> 1);
    const int P = GEMM_GRID * 2;

    short* __restrict__ H = half ? Hr : Hl;

    short8 Wf[8][4];
#pragma unroll
    for (int t = 0; t < 8; ++t)
#pragma unroll
        for (int kk = 0; kk < 4; ++kk)
            Wf[t][kk] = *(const short8*)(BT + (half * 128 + t * 16 + l16) * DIM + kk * 32 + quad * 8);

    for (int s = pair; s < NT_TILES; s += P) {
        long arow = (long)s * 16 + l16;

        short8 xf[4];
#pragma unroll
        for (int kk = 0; kk < 4; ++kk) {
            f32x4 a0 = *(const f32x4*)(Af + arow * DIM + kk * 32 + quad * 8);
            f32x4 a1 = *(const f32x4*)(Af + arow * DIM + kk * 32 + quad * 8 + 4);
            unsigned* xu = (unsigned*)&xf[kk];
            xu[0] = f2b2u(a0[0], a0[1]);
            xu[1] = f2b2u(a0[2], a0[3]);
            xu[2] = f2b2u(a1[0], a1[1]);
            xu[3] = f2b2u(a1[2], a1[3]);
        }

        f32x4 acc[8];
#pragma unroll
        for (int t = 0; t < 8; ++t)
#pragma unroll
            for (int r = 0; r < 4; ++r) acc[t][r] = 0.f;

#pragma unroll
        for (int kk = 0; kk < 4; ++kk)
#pragma unroll
            for (int t = 0; t < 8; ++t)
                acc[t] = __builtin_amdgcn_mfma_f32_16x16x32_bf16(Wf[t][kk], xf[kk], acc[t], 0, 0, 0);

#pragma unroll
        for (int t = 0; t < 8; ++t) {
            u32x2 o;
            o[0] = f2b2u(acc[t][0], acc[t][1]);
            o[1] = f2b2u(acc[t][2], acc[t][3]);
            *(u32x2*)(H + arow * DIM + t * 16 + quad * 4) = o;
        }
    }
}

// ---------------- gather-mean: one wave per node, 4 edges per load, 16B/lane, packed f32 acc ----

__device__ __forceinline__ void gather_mean(const short* __restrict__ Hl,
                                            const int* __restrict__ rowptr,
                                            const int* __restrict__ adj,
                                            int node, int lane, f32x2 sum[4], float& inv) {
    int g  = lane >> 4;
    int f0 = (lane & 15) << 3;
    int beg = rowptr[node];
    int deg = rowptr[node + 1] - beg;
#pragma unroll
    for (int d = 0; d < 4; ++d) { sum[d][0] = 0.f; sum[d][1] = 0.f; }

    int av = (lane < deg) ? adj[beg + lane] : 0;
    int degc = deg < 64 ? deg : 64;

    u32x4 h0;
    bool v0 = false;
    if (degc > 0) {
        int idx = __shfl(av, g, 64);
        v0 = g < degc;
        if (v0) h0 = *(const u32x4*)(Hl + (long)idx * DIM + f0);
    }
    for (int e0 = 4; e0 < degc; e0 += 4) {
        int idx = __shfl(av, e0 + g, 64);
        bool v1 = (e0 + g) < degc;
        u32x4 h1;
        if (v1) h1 = *(const u32x4*)(Hl + (long)idx * DIM + f0);
        if (v0) {
#pragma unroll
            for (int d = 0; d < 4; ++d) sum[d] += b2f2(h0[d]);
        }
        h0 = h1; v0 = v1;
    }
    if (v0) {
#pragma unroll
        for (int d = 0; d < 4; ++d) sum[d] += b2f2(h0[d]);
    }
    // rare fallback: degree > 64
    for (int e0 = 64; e0 < deg; e0 += 4) {
        int e = e0 + g;
        if (e < deg) {
            int idx = adj[beg + e];
            u32x4 h = *(const u32x4*)(Hl + (long)idx * DIM + f0);
#pragma unroll
            for (int d = 0; d < 4; ++d) sum[d] += b2f2(h[d]);
        }
    }
    // reduce across the 4 edge-slots (lanes xor 16, 32)
#pragma unroll
    for (int d = 0; d < 4; ++d)
#pragma unroll
        for (int c = 0; c < 2; ++c) {
            sum[d][c] += __shfl_xor(sum[d][c], 16, 64);
            sum[d][c] += __shfl_xor(sum[d][c], 32, 64);
        }
    inv = deg > 0 ? 1.f / (float)deg : 0.f;
}

// layer-1 agg fused with layer-2 projections:
// x1 = relu(mean(Hl[nbrs]) + Hr + b1)  (in registers, fp32)
// S[node] = (x1.u_p, x1.u_q)   -- gathered by layer-2
// T[node] = (x1.v_p, x1.v_q)   -- self term
__global__ void agg1_k(const short* __restrict__ Hl, const short* __restrict__ Hr,
                       const int* __restrict__ rowptr, const int* __restrict__ adj,
                       const float* __restrict__ b1,
                       const float* __restrict__ up, const float* __restrict__ uq,
                       const float* __restrict__ vp, const float* __restrict__ vq,
                       float2* __restrict__ S, float2* __restrict__ T) {
    int lane = threadIdx.x & 63;
    int node = blockIdx.x * 4 + (threadIdx.x >> 6);
    int f0 = (lane & 15) << 3;
    if (node >= N_NODES) return;

    f32x2 sum[4]; float inv;
    gather_mean(Hl, rowptr, adj, node, lane, sum, inv);

    f32x4 bb0 = *(const f32x4*)(b1 + f0);
    f32x4 bb1 = *(const f32x4*)(b1 + f0 + 4);
    u32x4 hru = *(const u32x4*)(Hr + (long)node * DIM + f0);
    float x[8];
#pragma unroll
    for (int d = 0; d < 4; ++d) {
        f32x2 hr2 = b2f2(hru[d]);
        int j0 = 2 * d;
        float bias0 = (j0 < 4) ? bb0[j0] : bb1[j0 - 4];
        float bias1 = (j0 + 1 < 4) ? bb0[j0 + 1] : bb1[j0 - 3];
        x[j0]     = fmaxf(sum[d][0] * inv + hr2[0] + bias0, 0.f);
        x[j0 + 1] = fmaxf(sum[d][1] * inv + hr2[1] + bias1, 0.f);
    }

    f32x4 up0 = *(const f32x4*)(up + f0), up1 = *(const f32x4*)(up + f0 + 4);
    f32x4 uq0 = *(const f32x4*)(uq + f0), uq1 = *(const f32x4*)(uq + f0 + 4);
    f32x4 vp0 = *(const f32x4*)(vp + f0), vp1 = *(const f32x4*)(vp + f0 + 4);
    f32x4 vq0 = *(const f32x4*)(vq + f0), vq1 = *(const f32x4*)(vq + f0 + 4);
    float ap = 0.f, aq = 0.f, tp = 0.f, tq = 0.f;
#pragma unroll
    for (int j = 0; j < 8; ++j) {
        float upj = (j < 4) ? up0[j] : up1[j - 4];
        float uqj = (j < 4) ? uq0[j] : uq1[j - 4];
        float vpj = (j < 4) ? vp0[j] : vp1[j - 4];
        float vqj = (j < 4) ? vq0[j] : vq1[j - 4];
        ap += x[j] * upj;
        aq += x[j] * uqj;
        tp += x[j] * vpj;
        tq += x[j] * vqj;
    }
#pragma unroll
    for (int m = 1; m <= 8; m <<= 1) {
        ap += __shfl_xor(ap, m, 64);
        aq += __shfl_xor(aq, m, 64);
        tp += __shfl_xor(tp, m, 64);
        tq += __shfl_xor(tq, m, 64);
    }
    if (lane == 0) {
        S[node] = make_float2(ap, aq);
        T[node] = make_float2(tp, tq);
    }
}

// layer-2: p[n] = mean_nbrs(S.x) + T.x + c.x ; q likewise. 8B gather per edge.
__global__ void agg2_k(const int* __restrict__ rowptr, const int* __restrict__ adj,
                       const float2* __restrict__ S, const float2* __restrict__ T,
                       const float2* __restrict__ cpq,
                       float* __restrict__ p, float* __restrict__ q) {
    int lane = threadIdx.x & 63;
    int wavei = blockIdx.x * 4 + (threadIdx.x >> 6);
    int slot = lane & 3;
    int node = wavei * 16 + (lane >> 2);
    if (node >= N_NODES) return;
    int beg = rowptr[node], end = rowptr[node + 1];
    float sp = 0.f, sq = 0.f;
    for (int e = beg + slot; e < end; e += 4) {
        float2 v = S[adj[e]];
        sp += v.x; sq += v.y;
    }
    sp += __shfl_xor(sp, 1, 64); sp += __shfl_xor(sp, 2, 64);
    sq += __shfl_xor(sq, 1, 64); sq += __shfl_xor(sq, 2, 64);
    if (slot == 0) {
        int deg = end - beg;
        float inv = deg > 0 ? 1.f / (float)deg : 0.f;
        float2 t = T[node];
        float2 c = *cpq;
        p[node] = sp * inv + t.x + c.x;
        q[node] = sq * inv + t.y + c.y;
    }
}

__global__ void out_k(const int* __restrict__ eli, const float* __restrict__ p,
                      const float* __restrict__ q, const float* __restrict__ blin,
                      float* __restrict__ out) {
    int i = blockIdx.x * blockDim.x + threadIdx.x;
    if (i < N_LABELS) out[i] = p[eli[i]] + q[eli[N_LABELS + i]] + blin[0];
}

// ---------------- launch ----------------

extern "C" void kernel_launch(void* const* d_in, const int* in_sizes, int n_in,
                              void* d_out, int out_size, void* d_ws, size_t ws_size,
                              hipStream_t stream) {
    const int*   edge_index = (const int*)d_in[0];
    const int*   eli        = (const int*)d_in[1];
    const float* emb        = (const float*)d_in[2];
    const float* W1l        = (const float*)d_in[3];
    const float* b1         = (const float*)d_in[4];
    const float* W1r        = (const float*)d_in[5];
    const float* W2l        = (const float*)d_in[6];
    const float* b2         = (const float*)d_in[7];
    const float* W2r        = (const float*)d_in[8];
    const float* Wlin       = (const float*)d_in[9];
    const float* blin       = (const float*)d_in[10];
    float* out = (float*)d_out;

    char* ws = (char*)d_ws;
    size_t off = 0;
    auto alloc = [&](size_t bytes) -> void* {
        off = (off + 255) & ~(size_t)255;
        void* ptr = ws + off;
        off += bytes;
        return ptr;
    };

    short* Hl  = (short*)alloc((size_t)N_NODES * DIM * 2);
    short* Hr  = (short*)alloc((size_t)N_NODES * DIM * 2);
    short* BT1 = (short*)alloc(256 * 128 * 2);
    float* up = (float*)alloc(128 * 4);
    float* uq = (float*)alloc(128 * 4);
    float* vp = (float*)alloc(128 * 4);
    float* vq = (float*)alloc(128 * 4);
    float2* cpq = (float2*)alloc(8);
    int* cnt      = (int*)alloc((size_t)N_NODES * 4);
    int* rowptr   = (int*)alloc((size_t)(N_NODES + 1) * 4);
    int* widx     = (int*)alloc((size_t)N_NODES * 4);
    int* adj      = (int*)alloc((size_t)N_EDGES * 4);
    int* partials = (int*)alloc(NPARTS * 4);
    float2* S     = (float2*)alloc((size_t)N_NODES * 8);
    float2* T     = (float2*)alloc((size_t)N_NODES * 8);
    float* p      = (float*)alloc((size_t)N_NODES * 4);
    float* q      = (float*)alloc((size_t)N_NODES * 4);

    // prep: weights + projections + cnt zero-init (fused memset)
    prep_k<<<130 + NPARTS, 256, 0, stream>>>(W1l, W1r, BT1, W2l, W2r, Wlin, b2,
                                             up, uq, vp, vq, cpq, cnt);

    // CSR build
    count_k<<<(N_EDGES + 255) / 256, 256, 0, stream>>>(edge_index, cnt);
    scan1_k<<<NPARTS, 256, 0, stream>>>(cnt, rowptr, partials);
    scanB_k<<<NPARTS, 512, 0, stream>>>(partials, rowptr, widx);
    fill_k<<<(N_EDGES + 255) / 256, 256, 0, stream>>>(edge_index, widx, adj);

    // layer 1 GEMM (emb f32 read + bf16 convert fused)
    gemm_k<<<GEMM_GRID, 256, 0, stream>>>(emb, BT1, Hl, Hr);

    // layer-1 aggregation fused with layer-2 projections
    agg1_k<<<N_NODES / 4, 256, 0, stream>>>(Hl, Hr, rowptr, adj, b1, up, uq, vp, vq, S, T);

    // layer-2 (8B-per-edge gather) + predictor
    agg2_k<<<(N_NODES + 63) / 64, 256, 0, stream>>>(rowptr, adj, S, T, cpq, p, q);
    out_k<<<(N_LABELS + 255) / 256, 256, 0, stream>>>(eli, p, q, blin, out);
}